// Round 8
// baseline (731.320 us; speedup 1.0000x reference)
//
#include <hip/hip_runtime.h>
#include <hip/hip_bf16.h>
#include <hip/hip_cooperative_groups.h>
#include <math.h>

namespace cg = cooperative_groups;

#define BATCH 8192
#define SEQ 50
#define EMB 512
#define VOCAB 100000
#define NCHUNK 4
#define CHUNK_V 25000   // vocab rows per chunk
#define CONVB 512       // conv-role blocks; bag-role = blocks [512,1024)

typedef __attribute__((ext_vector_type(8))) short bf16x8;
typedef __attribute__((ext_vector_type(4))) float f32x4;
typedef __attribute__((ext_vector_type(4))) float fvec4;

static __device__ __forceinline__ ushort f2b(float v) {
  __hip_bfloat16 h = __float2bfloat16(v);
  return *reinterpret_cast<ushort*>(&h);
}
static __device__ __forceinline__ float b2f(ushort u) {
  unsigned int x = ((unsigned int)u) << 16;
  float f;
  __builtin_memcpy(&f, &x, 4);
  return f;
}

// ---------------------------------------------------------------------------
// Fused cooperative conv(fp32->fp8) || embedding-bag pipeline.
// 1024 blocks x 256 thr (4 blocks/CU co-resident). Blocks [0,512): convert
// vocab chunk s at stage s. Blocks [512,1024): at stage s accumulate the
// contributions of ids falling in chunk s-1 (one wave per 4 batch rows,
// acc[4][8] fp32 in registers across stages). grid.sync() between stages.
// Overlaps HBM-streaming convert with L3-scatter-bound gather.
// ---------------------------------------------------------------------------
__global__ __launch_bounds__(256, 4) void fused_conv_bag(const int* __restrict__ ids,
                                                         const float* __restrict__ E,
                                                         unsigned char* __restrict__ E8,
                                                         ushort* __restrict__ X) {
  cg::grid_group grid = cg::this_grid();
  const int b = blockIdx.x;
  const int tid = threadIdx.x;
  const bool isConv = (b < CONVB);
  const int w = tid >> 6;
  const int l = tid & 63;

  __shared__ int sid[16][SEQ];  // bag role: 16 rows' ids
  float acc[4][8];
#pragma unroll
  for (int r = 0; r < 4; ++r)
#pragma unroll
    for (int k = 0; k < 8; ++k) acc[r][k] = 0.f;

  if (!isConv) {
    const int rowBase = (b - CONVB) * 16;
    for (int k = tid; k < 16 * SEQ; k += 256) sid[k / SEQ][k % SEQ] = ids[rowBase * SEQ + k];
    __syncthreads();
  }

  for (int stage = 0; stage <= NCHUNK; ++stage) {
    if (stage < NCHUNK && isConv) {
      // Convert chunk `stage`: CHUNK_V*EMB = 12.8M elems, 8 per thread-iter.
      const size_t base = (size_t)stage * CHUNK_V * EMB;
      const int t = b * 256 + tid;  // 0..131071
      for (int u = t; u < CHUNK_V * EMB / 8; u += CONVB * 256) {
        const size_t idx = base + (size_t)u * 8;
        const fvec4 a = __builtin_nontemporal_load(reinterpret_cast<const fvec4*>(E + idx));
        const fvec4 bb = __builtin_nontemporal_load(reinterpret_cast<const fvec4*>(E + idx + 4));
        int r0 = 0, r1 = 0;
        r0 = __builtin_amdgcn_cvt_pk_fp8_f32(a[0], a[1], r0, false);
        r0 = __builtin_amdgcn_cvt_pk_fp8_f32(a[2], a[3], r0, true);
        r1 = __builtin_amdgcn_cvt_pk_fp8_f32(bb[0], bb[1], r1, false);
        r1 = __builtin_amdgcn_cvt_pk_fp8_f32(bb[2], bb[3], r1, true);
        int2 o;
        o.x = r0;
        o.y = r1;
        *reinterpret_cast<int2*>(&E8[idx]) = o;
      }
    }
    if (stage >= 1 && !isConv) {
      const int lo = (stage - 1) * CHUNK_V;
#pragma unroll
      for (int r = 0; r < 4; ++r) {
        const int rl = w * 4 + r;
#pragma unroll 5
        for (int i = 0; i < SEQ; ++i) {
          const int id = sid[rl][i];  // wave-uniform -> uniform branch
          if ((unsigned)(id - lo) < (unsigned)CHUNK_V) {
            const int2 q =
                *reinterpret_cast<const int2*>(&E8[(size_t)id * EMB + l * 8]);
            const auto p0 = __builtin_amdgcn_cvt_pk_f32_fp8(q.x, false);
            const auto p1 = __builtin_amdgcn_cvt_pk_f32_fp8(q.x, true);
            const auto p2 = __builtin_amdgcn_cvt_pk_f32_fp8(q.y, false);
            const auto p3 = __builtin_amdgcn_cvt_pk_f32_fp8(q.y, true);
            acc[r][0] += p0[0]; acc[r][1] += p0[1];
            acc[r][2] += p1[0]; acc[r][3] += p1[1];
            acc[r][4] += p2[0]; acc[r][5] += p2[1];
            acc[r][6] += p3[0]; acc[r][7] += p3[1];
          }
        }
      }
    }
    if (stage < NCHUNK) grid.sync();
  }

  if (!isConv) {
    const int rowBase = (b - CONVB) * 16;
#pragma unroll
    for (int r = 0; r < 4; ++r) {
      ushort o[8];
#pragma unroll
      for (int k = 0; k < 8; ++k) o[k] = f2b(acc[r][k] * (1.0f / SEQ));
      *reinterpret_cast<int4*>(&X[(size_t)(rowBase + w * 4 + r) * EMB + l * 8]) =
          *reinterpret_cast<const int4*>(o);
    }
  }
}

// ---------------------------------------------------------------------------
// Serial fallback kernels (used if cooperative launch is unavailable).
// ---------------------------------------------------------------------------
__global__ __launch_bounds__(256) void convert_table_fp8(const float* __restrict__ E,
                                                         unsigned char* __restrict__ E8) {
  const size_t idx = ((size_t)blockIdx.x * 256 + threadIdx.x) * 8;  // < 51.2M exactly
  const fvec4 a = __builtin_nontemporal_load(reinterpret_cast<const fvec4*>(E + idx));
  const fvec4 b = __builtin_nontemporal_load(reinterpret_cast<const fvec4*>(E + idx + 4));
  int r0 = 0, r1 = 0;
  r0 = __builtin_amdgcn_cvt_pk_fp8_f32(a[0], a[1], r0, false);
  r0 = __builtin_amdgcn_cvt_pk_fp8_f32(a[2], a[3], r0, true);
  r1 = __builtin_amdgcn_cvt_pk_fp8_f32(b[0], b[1], r1, false);
  r1 = __builtin_amdgcn_cvt_pk_fp8_f32(b[2], b[3], r1, true);
  int2 o;
  o.x = r0;
  o.y = r1;
  *reinterpret_cast<int2*>(&E8[idx]) = o;
}

__global__ __launch_bounds__(256) void embed_bag_fp8(const int* __restrict__ ids,
                                                     const unsigned char* __restrict__ E8,
                                                     ushort* __restrict__ X) {
  __shared__ int sid[4][SEQ];
  const int tid = threadIdx.x;
  if (tid < 4 * SEQ) sid[tid / SEQ][tid % SEQ] = ids[blockIdx.x * 4 * SEQ + tid];
  __syncthreads();
  const int w = tid >> 6;
  const int l = tid & 63;
  const int row = blockIdx.x * 4 + w;
  float acc[8] = {};
#pragma unroll 5
  for (int i = 0; i < SEQ; ++i) {
    const int2 q = *reinterpret_cast<const int2*>(&E8[(size_t)sid[w][i] * EMB + l * 8]);
    const auto p0 = __builtin_amdgcn_cvt_pk_f32_fp8(q.x, false);
    const auto p1 = __builtin_amdgcn_cvt_pk_f32_fp8(q.x, true);
    const auto p2 = __builtin_amdgcn_cvt_pk_f32_fp8(q.y, false);
    const auto p3 = __builtin_amdgcn_cvt_pk_f32_fp8(q.y, true);
    acc[0] += p0[0]; acc[1] += p0[1];
    acc[2] += p1[0]; acc[3] += p1[1];
    acc[4] += p2[0]; acc[5] += p2[1];
    acc[6] += p3[0]; acc[7] += p3[1];
  }
  ushort r[8];
#pragma unroll
  for (int k = 0; k < 8; ++k) r[k] = f2b(acc[k] * (1.0f / SEQ));
  *reinterpret_cast<int4*>(&X[(size_t)row * EMB + l * 8]) = *reinterpret_cast<const int4*>(r);
}

__global__ __launch_bounds__(256) void embed_bag_f32(const int* __restrict__ ids,
                                                     const float* __restrict__ E,
                                                     ushort* __restrict__ X) {
  __shared__ int sid[SEQ];
  const int row = blockIdx.x;
  const int tid = threadIdx.x;
  if (tid < SEQ) sid[tid] = ids[row * SEQ + tid];
  __syncthreads();
  const int c = tid * 2;
  float ax = 0.f, ay = 0.f;
#pragma unroll 5
  for (int i = 0; i < SEQ; ++i) {
    const float2 v = *reinterpret_cast<const float2*>(&E[(size_t)sid[i] * EMB + c]);
    ax += v.x;
    ay += v.y;
  }
  ushort2 o;
  o.x = f2b(ax * (1.0f / SEQ));
  o.y = f2b(ay * (1.0f / SEQ));
  *reinterpret_cast<ushort2*>(&X[(size_t)row * EMB + c]) = o;
}

// ---------------------------------------------------------------------------
// Kernel 0: weight convert + transpose. Wt[n][k] = bf16(W[k][n]).
// ---------------------------------------------------------------------------
__global__ __launch_bounds__(256) void convert_weights(
    const float* __restrict__ W0, const float* __restrict__ W1,
    const float* __restrict__ W2, const float* __restrict__ W3,
    ushort* __restrict__ T0, ushort* __restrict__ T1,
    ushort* __restrict__ T2, ushort* __restrict__ T3) {
  const int idx = blockIdx.x * 256 + threadIdx.x;
  const int which = blockIdx.y;
  const float* W;
  ushort* T;
  int K, N;
  if (which == 0)      { W = W0; T = T0; K = 512; N = 512; }
  else if (which == 1) { W = W1; T = T1; K = 512; N = 256; }
  else if (which == 2) { W = W2; T = T2; K = 256; N = 128; }
  else                 { W = W3; T = T3; K = 128; N = 64; }
  if (idx >= K * N) return;
  const int n = idx / K;
  const int k = idx - n * K;
  T[idx] = f2b(W[k * N + n]);
}

// ---------------------------------------------------------------------------
// Kernel 2: bf16 MFMA GEMM + bias + ReLU, bf16 out. 128x64 tile, BK=64.
// ---------------------------------------------------------------------------
template <int K, int N, bool RELU>
__global__ __launch_bounds__(256) void gemm_mfma(const ushort* __restrict__ A,   // [M][K] bf16
                                                 const ushort* __restrict__ Bt,  // [N][K] bf16
                                                 const float* __restrict__ bias, // [N]
                                                 ushort* __restrict__ C) {       // [M][N] bf16
  __shared__ ushort As[128][72];
  __shared__ ushort Bs[64][72];
  const int tid = threadIdx.x;
  const int w = tid >> 6;
  const int l = tid & 63;
  const int r16 = l & 15;
  const int khi = l >> 4;
  const int rowBase = blockIdx.y * 128;
  const int colBase = blockIdx.x * 64;

  f32x4 acc[2][4] = {};

  for (int kt = 0; kt < K; kt += 64) {
#pragma unroll
    for (int i = 0; i < 4; ++i) {
      const int idx = i * 256 + tid;
      const int r = idx >> 3;
      const int kq = (idx & 7) * 8;
      *reinterpret_cast<int4*>(&As[r][kq]) =
          *reinterpret_cast<const int4*>(&A[(size_t)(rowBase + r) * K + kt + kq]);
    }
#pragma unroll
    for (int i = 0; i < 2; ++i) {
      const int idx = i * 256 + tid;
      const int n = idx >> 3;
      const int kq = (idx & 7) * 8;
      *reinterpret_cast<int4*>(&Bs[n][kq]) =
          *reinterpret_cast<const int4*>(&Bt[(size_t)(colBase + n) * K + kt + kq]);
    }
    __syncthreads();
#pragma unroll
    for (int q = 0; q < 2; ++q) {
      const int ko = q * 32 + khi * 8;
      const bf16x8 a0 = *reinterpret_cast<const bf16x8*>(&As[w * 32 + r16][ko]);
      const bf16x8 a1 = *reinterpret_cast<const bf16x8*>(&As[w * 32 + 16 + r16][ko]);
      const bf16x8 b0 = *reinterpret_cast<const bf16x8*>(&Bs[r16][ko]);
      const bf16x8 b1 = *reinterpret_cast<const bf16x8*>(&Bs[16 + r16][ko]);
      const bf16x8 b2 = *reinterpret_cast<const bf16x8*>(&Bs[32 + r16][ko]);
      const bf16x8 b3 = *reinterpret_cast<const bf16x8*>(&Bs[48 + r16][ko]);
      acc[0][0] = __builtin_amdgcn_mfma_f32_16x16x32_bf16(a0, b0, acc[0][0], 0, 0, 0);
      acc[0][1] = __builtin_amdgcn_mfma_f32_16x16x32_bf16(a0, b1, acc[0][1], 0, 0, 0);
      acc[0][2] = __builtin_amdgcn_mfma_f32_16x16x32_bf16(a0, b2, acc[0][2], 0, 0, 0);
      acc[0][3] = __builtin_amdgcn_mfma_f32_16x16x32_bf16(a0, b3, acc[0][3], 0, 0, 0);
      acc[1][0] = __builtin_amdgcn_mfma_f32_16x16x32_bf16(a1, b0, acc[1][0], 0, 0, 0);
      acc[1][1] = __builtin_amdgcn_mfma_f32_16x16x32_bf16(a1, b1, acc[1][1], 0, 0, 0);
      acc[1][2] = __builtin_amdgcn_mfma_f32_16x16x32_bf16(a1, b2, acc[1][2], 0, 0, 0);
      acc[1][3] = __builtin_amdgcn_mfma_f32_16x16x32_bf16(a1, b3, acc[1][3], 0, 0, 0);
    }
    __syncthreads();
  }

#pragma unroll
  for (int n = 0; n < 4; ++n) {
    const float bv = bias[colBase + n * 16 + r16];
#pragma unroll
    for (int m = 0; m < 2; ++m) {
#pragma unroll
      for (int e = 0; e < 4; ++e) {
        const int rr = rowBase + w * 32 + m * 16 + khi * 4 + e;
        float v = acc[m][n][e] + bv;
        if (RELU) v = fmaxf(v, 0.f);
        C[(size_t)rr * N + colBase + n * 16 + r16] = f2b(v);
      }
    }
  }
}

// ---------------------------------------------------------------------------
// Kernel 3: final layer (K=64, N=3) + softmax. bf16 input, fp32 out.
// ---------------------------------------------------------------------------
__global__ __launch_bounds__(256) void final_softmax(const ushort* __restrict__ X,
                                                     const float* __restrict__ W,    // [64][3]
                                                     const float* __restrict__ bias, // [3]
                                                     float* __restrict__ Out) {      // [B][3]
  __shared__ float sw[64 * 3];
  __shared__ float sb[3];
  const int tid = threadIdx.x;
  if (tid < 64 * 3) sw[tid] = W[tid];
  if (tid < 3) sb[tid] = bias[tid];
  __syncthreads();

  const int row = blockIdx.x * 256 + tid;
  float d0 = sb[0], d1 = sb[1], d2 = sb[2];
#pragma unroll
  for (int k = 0; k < 64; k += 8) {
    const int4 xr = *reinterpret_cast<const int4*>(&X[(size_t)row * 64 + k]);
    const ushort* xp = reinterpret_cast<const ushort*>(&xr);
#pragma unroll
    for (int u = 0; u < 8; ++u) {
      const float x = b2f(xp[u]);
      d0 = fmaf(x, sw[(k + u) * 3 + 0], d0);
      d1 = fmaf(x, sw[(k + u) * 3 + 1], d1);
      d2 = fmaf(x, sw[(k + u) * 3 + 2], d2);
    }
  }
  const float m = fmaxf(d0, fmaxf(d1, d2));
  const float e0 = expf(d0 - m);
  const float e1 = expf(d1 - m);
  const float e2 = expf(d2 - m);
  const float inv = 1.0f / (e0 + e1 + e2);
  Out[(size_t)row * 3 + 0] = e0 * inv;
  Out[(size_t)row * 3 + 1] = e1 * inv;
  Out[(size_t)row * 3 + 2] = e2 * inv;
}

// ---------------------------------------------------------------------------
extern "C" void kernel_launch(void* const* d_in, const int* in_sizes, int n_in,
                              void* d_out, int out_size, void* d_ws, size_t ws_size,
                              hipStream_t stream) {
  const int* ids = (const int*)d_in[0];
  const float* E = (const float*)d_in[1];
  const float* W0 = (const float*)d_in[2];
  const float* b0 = (const float*)d_in[3];
  const float* W1 = (const float*)d_in[4];
  const float* b1 = (const float*)d_in[5];
  const float* W2 = (const float*)d_in[6];
  const float* b2 = (const float*)d_in[7];
  const float* W3 = (const float*)d_in[8];
  const float* b3 = (const float*)d_in[9];
  const float* W4 = (const float*)d_in[10];
  const float* b4 = (const float*)d_in[11];
  float* out = (float*)d_out;

  // Workspace: [Wt0..Wt3 | pad->1MB | xA 8MB | xB 8MB | E8 51.2MB]
  ushort* wt0 = (ushort*)d_ws;
  ushort* wt1 = wt0 + 512 * 512;
  ushort* wt2 = wt1 + 512 * 256;
  ushort* wt3 = wt2 + 256 * 128;
  ushort* xA = (ushort*)((char*)d_ws + (1u << 20));
  ushort* xB = xA + (size_t)BATCH * EMB;
  unsigned char* E8 = (unsigned char*)((char*)d_ws + 17u * (1u << 20));
  const size_t need = 17u * (1u << 20) + (size_t)VOCAB * EMB;
  const bool big = ws_size >= need;

  convert_weights<<<dim3(1024, 4), 256, 0, stream>>>(W0, W1, W2, W3, wt0, wt1, wt2, wt3);
  if (big) {
    void* args[] = {(void*)&ids, (void*)&E, (void*)&E8, (void*)&xA};
    hipError_t err = hipLaunchCooperativeKernel((void*)fused_conv_bag, dim3(1024),
                                                dim3(256), args, 0, stream);
    if (err != hipSuccess) {
      // Serial fallback (round-6 path).
      convert_table_fp8<<<25000, 256, 0, stream>>>(E, E8);
      embed_bag_fp8<<<BATCH / 4, 256, 0, stream>>>(ids, E8, xA);
    }
  } else {
    embed_bag_f32<<<BATCH, 256, 0, stream>>>(ids, E, xA);
  }
  gemm_mfma<512, 512, true><<<dim3(8, 64), 256, 0, stream>>>(xA, wt0, b0, xB);       // xB [8192,512]
  gemm_mfma<512, 256, true><<<dim3(4, 64), 256, 0, stream>>>(xB, wt1, b1, xA);       // xA [8192,256]
  gemm_mfma<256, 128, true><<<dim3(2, 64), 256, 0, stream>>>(xA, wt2, b2, xB);       // xB [8192,128]
  gemm_mfma<128, 64, true><<<dim3(1, 64), 256, 0, stream>>>(xB, wt3, b3, xA);        // xA [8192,64]
  final_softmax<<<BATCH / 256, 256, 0, stream>>>(xA, W4, b4, out);                   // out [8192,3]
}

// Round 9
// 126.136 us; speedup vs baseline: 5.7979x; 5.7979x over previous
//
#include <hip/hip_runtime.h>
#include <hip/hip_bf16.h>
#include <math.h>

#define BATCH 8192
#define SEQ 50
#define EMB 512
#define VOCAB 100000

typedef __attribute__((ext_vector_type(8))) short bf16x8;
typedef __attribute__((ext_vector_type(4))) float f32x4;
typedef __attribute__((ext_vector_type(4))) float fvec4;

static __device__ __forceinline__ ushort f2b(float v) {
  __hip_bfloat16 h = __float2bfloat16(v);
  return *reinterpret_cast<ushort*>(&h);
}
static __device__ __forceinline__ float b2f(ushort u) {
  unsigned int x = ((unsigned int)u) << 16;
  float f;
  __builtin_memcpy(&f, &x, 4);
  return f;
}

// ---------------------------------------------------------------------------
// Kernel -1: table convert fp32 -> fp8 e4m3 (OCP, HW cvt, RNE).
// 256 MB streamed at HBM ceiling (~41 us) — measured at its floor.
// Nontemporal fp32 reads keep the dying fp32 stream from evicting the fp8
// table (written normally -> L3-resident for the bag).
// ---------------------------------------------------------------------------
__global__ __launch_bounds__(256) void convert_table_fp8(const float* __restrict__ E,
                                                         unsigned char* __restrict__ E8) {
  const size_t idx = ((size_t)blockIdx.x * 256 + threadIdx.x) * 8;  // < 51.2M exactly
  const fvec4 a = __builtin_nontemporal_load(reinterpret_cast<const fvec4*>(E + idx));
  const fvec4 b = __builtin_nontemporal_load(reinterpret_cast<const fvec4*>(E + idx + 4));
  int r0 = 0, r1 = 0;
  r0 = __builtin_amdgcn_cvt_pk_fp8_f32(a[0], a[1], r0, false);
  r0 = __builtin_amdgcn_cvt_pk_fp8_f32(a[2], a[3], r0, true);
  r1 = __builtin_amdgcn_cvt_pk_fp8_f32(b[0], b[1], r1, false);
  r1 = __builtin_amdgcn_cvt_pk_fp8_f32(b[2], b[3], r1, true);
  int2 o;
  o.x = r0;
  o.y = r1;
  *reinterpret_cast<int2*>(&E8[idx]) = o;
}

// ---------------------------------------------------------------------------
// Kernel 0: weight convert + transpose. Wt[n][k] = bf16(W[k][n]).
// ---------------------------------------------------------------------------
__global__ __launch_bounds__(256) void convert_weights(
    const float* __restrict__ W0, const float* __restrict__ W1,
    const float* __restrict__ W2, const float* __restrict__ W3,
    ushort* __restrict__ T0, ushort* __restrict__ T1,
    ushort* __restrict__ T2, ushort* __restrict__ T3) {
  const int idx = blockIdx.x * 256 + threadIdx.x;
  const int which = blockIdx.y;
  const float* W;
  ushort* T;
  int K, N;
  if (which == 0)      { W = W0; T = T0; K = 512; N = 512; }
  else if (which == 1) { W = W1; T = T1; K = 512; N = 256; }
  else if (which == 2) { W = W2; T = T2; K = 256; N = 128; }
  else                 { W = W3; T = T3; K = 128; N = 64; }
  if (idx >= K * N) return;
  const int n = idx / K;
  const int k = idx - n * K;
  T[idx] = f2b(W[k * N + n]);
}

// ---------------------------------------------------------------------------
// Kernel 1a: embedding bag over fp8 table. One WAVE per batch row; lane
// covers 8 fp8 cols (8 B load -> one 512 B contiguous row-read per wave).
// 204.8 MB demand at the measured scattered-512B service rate (~3.4 TB/s);
// shown insensitive to ordering (r7 sort null), slicing (r5 regress), and
// producer/consumer coordination (r8 regress). 4 rows per 256-thread block.
// ---------------------------------------------------------------------------
__global__ __launch_bounds__(256) void embed_bag_fp8(const int* __restrict__ ids,
                                                     const unsigned char* __restrict__ E8,
                                                     ushort* __restrict__ X) {
  __shared__ int sid[4][SEQ];
  const int tid = threadIdx.x;
  if (tid < 4 * SEQ) sid[tid / SEQ][tid % SEQ] = ids[blockIdx.x * 4 * SEQ + tid];
  __syncthreads();
  const int w = tid >> 6;
  const int l = tid & 63;
  const int row = blockIdx.x * 4 + w;
  float acc[8] = {};
#pragma unroll 5
  for (int i = 0; i < SEQ; ++i) {
    const int2 q = *reinterpret_cast<const int2*>(&E8[(size_t)sid[w][i] * EMB + l * 8]);
    const auto p0 = __builtin_amdgcn_cvt_pk_f32_fp8(q.x, false);
    const auto p1 = __builtin_amdgcn_cvt_pk_f32_fp8(q.x, true);
    const auto p2 = __builtin_amdgcn_cvt_pk_f32_fp8(q.y, false);
    const auto p3 = __builtin_amdgcn_cvt_pk_f32_fp8(q.y, true);
    acc[0] += p0[0]; acc[1] += p0[1];
    acc[2] += p1[0]; acc[3] += p1[1];
    acc[4] += p2[0]; acc[5] += p2[1];
    acc[6] += p3[0]; acc[7] += p3[1];
  }
  ushort r[8];
#pragma unroll
  for (int k = 0; k < 8; ++k) r[k] = f2b(acc[k] * (1.0f / SEQ));
  *reinterpret_cast<int4*>(&X[(size_t)row * EMB + l * 8]) = *reinterpret_cast<const int4*>(r);
}

// ---------------------------------------------------------------------------
// Kernel 1b (fallback, small ws): fp32-table bag, bf16 out. Block per row.
// ---------------------------------------------------------------------------
__global__ __launch_bounds__(256) void embed_bag_f32(const int* __restrict__ ids,
                                                     const float* __restrict__ E,
                                                     ushort* __restrict__ X) {
  __shared__ int sid[SEQ];
  const int row = blockIdx.x;
  const int tid = threadIdx.x;
  if (tid < SEQ) sid[tid] = ids[row * SEQ + tid];
  __syncthreads();
  const int c = tid * 2;
  float ax = 0.f, ay = 0.f;
#pragma unroll 5
  for (int i = 0; i < SEQ; ++i) {
    const float2 v = *reinterpret_cast<const float2*>(&E[(size_t)sid[i] * EMB + c]);
    ax += v.x;
    ay += v.y;
  }
  ushort2 o;
  o.x = f2b(ax * (1.0f / SEQ));
  o.y = f2b(ay * (1.0f / SEQ));
  *reinterpret_cast<ushort2*>(&X[(size_t)row * EMB + c]) = o;
}

// ---------------------------------------------------------------------------
// Kernel 2: bf16 MFMA GEMM + bias + ReLU, bf16 out. 128x64 tile, BK=64.
// ---------------------------------------------------------------------------
template <int K, int N, bool RELU>
__global__ __launch_bounds__(256) void gemm_mfma(const ushort* __restrict__ A,   // [M][K] bf16
                                                 const ushort* __restrict__ Bt,  // [N][K] bf16
                                                 const float* __restrict__ bias, // [N]
                                                 ushort* __restrict__ C) {       // [M][N] bf16
  __shared__ ushort As[128][72];
  __shared__ ushort Bs[64][72];
  const int tid = threadIdx.x;
  const int w = tid >> 6;
  const int l = tid & 63;
  const int r16 = l & 15;
  const int khi = l >> 4;
  const int rowBase = blockIdx.y * 128;
  const int colBase = blockIdx.x * 64;

  f32x4 acc[2][4] = {};

  for (int kt = 0; kt < K; kt += 64) {
#pragma unroll
    for (int i = 0; i < 4; ++i) {
      const int idx = i * 256 + tid;
      const int r = idx >> 3;
      const int kq = (idx & 7) * 8;
      *reinterpret_cast<int4*>(&As[r][kq]) =
          *reinterpret_cast<const int4*>(&A[(size_t)(rowBase + r) * K + kt + kq]);
    }
#pragma unroll
    for (int i = 0; i < 2; ++i) {
      const int idx = i * 256 + tid;
      const int n = idx >> 3;
      const int kq = (idx & 7) * 8;
      *reinterpret_cast<int4*>(&Bs[n][kq]) =
          *reinterpret_cast<const int4*>(&Bt[(size_t)(colBase + n) * K + kt + kq]);
    }
    __syncthreads();
#pragma unroll
    for (int q = 0; q < 2; ++q) {
      const int ko = q * 32 + khi * 8;
      const bf16x8 a0 = *reinterpret_cast<const bf16x8*>(&As[w * 32 + r16][ko]);
      const bf16x8 a1 = *reinterpret_cast<const bf16x8*>(&As[w * 32 + 16 + r16][ko]);
      const bf16x8 b0 = *reinterpret_cast<const bf16x8*>(&Bs[r16][ko]);
      const bf16x8 b1 = *reinterpret_cast<const bf16x8*>(&Bs[16 + r16][ko]);
      const bf16x8 b2 = *reinterpret_cast<const bf16x8*>(&Bs[32 + r16][ko]);
      const bf16x8 b3 = *reinterpret_cast<const bf16x8*>(&Bs[48 + r16][ko]);
      acc[0][0] = __builtin_amdgcn_mfma_f32_16x16x32_bf16(a0, b0, acc[0][0], 0, 0, 0);
      acc[0][1] = __builtin_amdgcn_mfma_f32_16x16x32_bf16(a0, b1, acc[0][1], 0, 0, 0);
      acc[0][2] = __builtin_amdgcn_mfma_f32_16x16x32_bf16(a0, b2, acc[0][2], 0, 0, 0);
      acc[0][3] = __builtin_amdgcn_mfma_f32_16x16x32_bf16(a0, b3, acc[0][3], 0, 0, 0);
      acc[1][0] = __builtin_amdgcn_mfma_f32_16x16x32_bf16(a1, b0, acc[1][0], 0, 0, 0);
      acc[1][1] = __builtin_amdgcn_mfma_f32_16x16x32_bf16(a1, b1, acc[1][1], 0, 0, 0);
      acc[1][2] = __builtin_amdgcn_mfma_f32_16x16x32_bf16(a1, b2, acc[1][2], 0, 0, 0);
      acc[1][3] = __builtin_amdgcn_mfma_f32_16x16x32_bf16(a1, b3, acc[1][3], 0, 0, 0);
    }
    __syncthreads();
  }

#pragma unroll
  for (int n = 0; n < 4; ++n) {
    const float bv = bias[colBase + n * 16 + r16];
#pragma unroll
    for (int m = 0; m < 2; ++m) {
#pragma unroll
      for (int e = 0; e < 4; ++e) {
        const int rr = rowBase + w * 32 + m * 16 + khi * 4 + e;
        float v = acc[m][n][e] + bv;
        if (RELU) v = fmaxf(v, 0.f);
        C[(size_t)rr * N + colBase + n * 16 + r16] = f2b(v);
      }
    }
  }
}

// ---------------------------------------------------------------------------
// Kernel 3: final layer (K=64, N=3) + softmax. bf16 input, fp32 out.
// ---------------------------------------------------------------------------
__global__ __launch_bounds__(256) void final_softmax(const ushort* __restrict__ X,
                                                     const float* __restrict__ W,    // [64][3]
                                                     const float* __restrict__ bias, // [3]
                                                     float* __restrict__ Out) {      // [B][3]
  __shared__ float sw[64 * 3];
  __shared__ float sb[3];
  const int tid = threadIdx.x;
  if (tid < 64 * 3) sw[tid] = W[tid];
  if (tid < 3) sb[tid] = bias[tid];
  __syncthreads();

  const int row = blockIdx.x * 256 + tid;
  float d0 = sb[0], d1 = sb[1], d2 = sb[2];
#pragma unroll
  for (int k = 0; k < 64; k += 8) {
    const int4 xr = *reinterpret_cast<const int4*>(&X[(size_t)row * 64 + k]);
    const ushort* xp = reinterpret_cast<const ushort*>(&xr);
#pragma unroll
    for (int u = 0; u < 8; ++u) {
      const float x = b2f(xp[u]);
      d0 = fmaf(x, sw[(k + u) * 3 + 0], d0);
      d1 = fmaf(x, sw[(k + u) * 3 + 1], d1);
      d2 = fmaf(x, sw[(k + u) * 3 + 2], d2);
    }
  }
  const float m = fmaxf(d0, fmaxf(d1, d2));
  const float e0 = expf(d0 - m);
  const float e1 = expf(d1 - m);
  const float e2 = expf(d2 - m);
  const float inv = 1.0f / (e0 + e1 + e2);
  Out[(size_t)row * 3 + 0] = e0 * inv;
  Out[(size_t)row * 3 + 1] = e1 * inv;
  Out[(size_t)row * 3 + 2] = e2 * inv;
}

// ---------------------------------------------------------------------------
extern "C" void kernel_launch(void* const* d_in, const int* in_sizes, int n_in,
                              void* d_out, int out_size, void* d_ws, size_t ws_size,
                              hipStream_t stream) {
  const int* ids = (const int*)d_in[0];
  const float* E = (const float*)d_in[1];
  const float* W0 = (const float*)d_in[2];
  const float* b0 = (const float*)d_in[3];
  const float* W1 = (const float*)d_in[4];
  const float* b1 = (const float*)d_in[5];
  const float* W2 = (const float*)d_in[6];
  const float* b2 = (const float*)d_in[7];
  const float* W3 = (const float*)d_in[8];
  const float* b3 = (const float*)d_in[9];
  const float* W4 = (const float*)d_in[10];
  const float* b4 = (const float*)d_in[11];
  float* out = (float*)d_out;

  // Workspace: [Wt0..Wt3 | pad->1MB | xA 8MB | xB 8MB | E8 51.2MB]
  ushort* wt0 = (ushort*)d_ws;
  ushort* wt1 = wt0 + 512 * 512;
  ushort* wt2 = wt1 + 512 * 256;
  ushort* wt3 = wt2 + 256 * 128;
  ushort* xA = (ushort*)((char*)d_ws + (1u << 20));
  ushort* xB = xA + (size_t)BATCH * EMB;
  unsigned char* E8 = (unsigned char*)((char*)d_ws + 17u * (1u << 20));
  const size_t need = 17u * (1u << 20) + (size_t)VOCAB * EMB;
  const bool big = ws_size >= need;

  convert_weights<<<dim3(1024, 4), 256, 0, stream>>>(W0, W1, W2, W3, wt0, wt1, wt2, wt3);
  if (big) {
    convert_table_fp8<<<25000, 256, 0, stream>>>(E, E8);        // 51.2M elems exactly
    embed_bag_fp8<<<BATCH / 4, 256, 0, stream>>>(ids, E8, xA);  // xA [8192,512]
  } else {
    embed_bag_f32<<<BATCH, 256, 0, stream>>>(ids, E, xA);
  }
  gemm_mfma<512, 512, true><<<dim3(8, 64), 256, 0, stream>>>(xA, wt0, b0, xB);       // xB [8192,512]
  gemm_mfma<512, 256, true><<<dim3(4, 64), 256, 0, stream>>>(xB, wt1, b1, xA);       // xA [8192,256]
  gemm_mfma<256, 128, true><<<dim3(2, 64), 256, 0, stream>>>(xA, wt2, b2, xB);       // xB [8192,128]
  gemm_mfma<128, 64, true><<<dim3(1, 64), 256, 0, stream>>>(xB, wt3, b3, xA);        // xA [8192,64]
  final_softmax<<<BATCH / 256, 256, 0, stream>>>(xA, W4, b4, out);                   // out [8192,3]
}